// Round 1
// baseline (600.595 us; speedup 1.0000x reference)
//
#include <hip/hip_runtime.h>
#include <cstdint>
#include <cstddef>

// CrossContext: VN attention block. B=4, C=64, N=2048, K=16, fp32.
constexpr int B_ = 4, C_ = 64, N_ = 2048, K_ = 16;
constexpr int D3 = 192;                    // 3*C
constexpr float EPS_ = 1e-6f, BNE_ = 1e-5f, NEG_ = 0.2f;
constexpr size_t S_ = (size_t)B_ * N_ * D3;   // 1,572,864 floats per tensor

// workspace float offsets
constexpr size_t OFF_PQ  = 0;        // Wq·x      [b][n][192] (o*3+v)
constexpr size_t OFF_DQ  = 1*S_;     // Dq·x
constexpr size_t OFF_UK  = 2*S_;     // Wk1·y  (gathered part)
constexpr size_t OFF_WK  = 3*S_;     // (Wk2-Wk1)·y (center part)
constexpr size_t OFF_UDK = 4*S_;
constexpr size_t OFF_WDK = 5*S_;
constexpr size_t OFF_UV  = 6*S_;
constexpr size_t OFF_WV  = 7*S_;
constexpr size_t OFF_UDV = 8*S_;
constexpr size_t OFF_WDV = 9*S_;
constexpr size_t OFF_QX  = 10*S_;    // finished Q branch
constexpr size_t OFF_DIST= 11*S_;                       // N*N, reused per batch
constexpr size_t OFF_SQ  = OFF_DIST + (size_t)N_*N_;    // B*N
constexpr size_t OFF_ST  = OFF_SQ + (size_t)B_*N_;      // 1024 floats stats
constexpr size_t OFF_IDX = OFF_ST + 1024;               // B*N*K ints
// total ≈ 21.6M floats ≈ 86.6 MB

__device__ __forceinline__ float wred_sum(float v) {
  #pragma unroll
  for (int off = 32; off > 0; off >>= 1) v += __shfl_xor(v, off, 64);
  return v;
}

__device__ __forceinline__ void amax2(float& v, int& i, float ov, int oi) {
  if (ov > v || (ov == v && oi < i)) { v = ov; i = oi; }
}

// VN BatchNorm(folded scale/shift) + LeakyReLU on one 3-vector.
__device__ __forceinline__ void vnlk(float& p0, float& p1, float& p2,
                                     float d0, float d1, float d2,
                                     float s, float sh) {
  float norm = sqrtf(p0*p0 + p1*p1 + p2*p2) + EPS_;
  float f = (norm * s + sh) / norm;          // norm_bn / norm
  p0 *= f; p1 *= f; p2 *= f;
  float dot = p0*d0 + p1*d1 + p2*d2;
  float dns = d0*d0 + d1*d1 + d2*d2;
  if (dot < 0.f) {
    float g = (1.f - NEG_) * dot / (dns + EPS_);
    p0 -= g*d0; p1 -= g*d1; p2 -= g*d2;
  }
}

// ---------------- transforms: out[b][n][o*3+v] = sum_c W[o][c] in[b][c][v][n] --
template<bool PAIR>
__device__ __forceinline__ void mm_tile(const float (*ys)[65], const float (*Wl)[129],
                                        float* __restrict__ out0, float* __restrict__ out1,
                                        int og, int ng, int b, int n0) {
  float accU[4][4][3] = {};
  float accW[4][4][3] = {};
  for (int c = 0; c < 64; ++c) {
    float w1[4], wd[4];
    #pragma unroll
    for (int i = 0; i < 4; ++i) {
      w1[i] = Wl[og*4 + i][c];
      if (PAIR) wd[i] = Wl[og*4 + i][64 + c] - w1[i];
    }
    #pragma unroll
    for (int jj = 0; jj < 4; ++jj) {
      #pragma unroll
      for (int v = 0; v < 3; ++v) {
        float yv = ys[c*3 + v][ng*4 + jj];
        #pragma unroll
        for (int i = 0; i < 4; ++i) {
          accU[i][jj][v] = fmaf(w1[i], yv, accU[i][jj][v]);
          if (PAIR) accW[i][jj][v] = fmaf(wd[i], yv, accW[i][jj][v]);
        }
      }
    }
  }
  #pragma unroll
  for (int jj = 0; jj < 4; ++jj) {
    int n = n0 + ng*4 + jj;
    size_t base = ((size_t)b*N_ + n)*D3 + og*12;
    alignas(16) float tmp[12];
    #pragma unroll
    for (int i = 0; i < 4; ++i)
      #pragma unroll
      for (int v = 0; v < 3; ++v) tmp[i*3+v] = accU[i][jj][v];
    float4* dst = (float4*)(out0 + base);
    const float4* s4 = (const float4*)tmp;
    dst[0] = s4[0]; dst[1] = s4[1]; dst[2] = s4[2];
    if (PAIR) {
      #pragma unroll
      for (int i = 0; i < 4; ++i)
        #pragma unroll
        for (int v = 0; v < 3; ++v) tmp[i*3+v] = accW[i][jj][v];
      float4* dst1 = (float4*)(out1 + base);
      dst1[0] = s4[0]; dst1[1] = s4[1]; dst1[2] = s4[2];
    }
  }
}

// grid (N/64, B, 2): z=0 -> x input (Wq,Dq), z=1 -> y input (Wk,Dk,Wv,Dv) + sq
__global__ __launch_bounds__(256) void transform_kernel(
    const float* __restrict__ x, const float* __restrict__ y,
    const float* __restrict__ Wq, const float* __restrict__ Dq,
    const float* __restrict__ Wk, const float* __restrict__ Dk,
    const float* __restrict__ Wv, const float* __restrict__ Dv,
    float* __restrict__ ws) {
  __shared__ float ys[D3][65];
  __shared__ float Wl[64][129];
  int t = threadIdx.x;
  int n0 = blockIdx.x * 64;
  int b = blockIdx.y;
  int src = blockIdx.z;
  const float* in = (src == 0 ? x : y) + (size_t)b * D3 * N_;
  #pragma unroll 4
  for (int i = 0; i < 48; ++i) {          // 192*64/256
    int idx = t + i*256;
    int d = idx >> 6, nl = idx & 63;
    ys[d][nl] = in[(size_t)d * N_ + n0 + nl];
  }
  __syncthreads();
  if (src == 1 && t < 64) {               // sq for kNN
    float s = 0.f;
    for (int d = 0; d < D3; ++d) { float v = ys[d][t]; s += v*v; }
    ws[OFF_SQ + (size_t)b*N_ + n0 + t] = s;
  }
  int og = t & 15, ng = t >> 4;
  if (src == 0) {
    for (int job = 0; job < 2; ++job) {
      const float* Wg = job ? Dq : Wq;
      float* out0 = ws + (job ? OFF_DQ : OFF_PQ);
      __syncthreads();
      for (int i = t; i < 4096; i += 256) Wl[i>>6][i&63] = Wg[i];
      __syncthreads();
      mm_tile<false>(ys, Wl, out0, nullptr, og, ng, b, n0);
    }
  } else {
    for (int job = 0; job < 4; ++job) {
      const float* Wg = (job==0)?Wk:(job==1)?Dk:(job==2)?Wv:Dv;
      float* out0 = ws + ((job==0)?OFF_UK:(job==1)?OFF_UDK:(job==2)?OFF_UV:OFF_UDV);
      float* out1 = ws + ((job==0)?OFF_WK:(job==1)?OFF_WDK:(job==2)?OFF_WV:OFF_WDV);
      __syncthreads();
      for (int i = t; i < 8192; i += 256) Wl[i>>7][i&127] = Wg[i];
      __syncthreads();
      mm_tile<true>(ys, Wl, out0, out1, og, ng, b, n0);
    }
  }
}

// ---------------- kNN: Gram matrix + neg dist, per batch -----------------------
// grid (N/64, N/64), block 256. dist[n][m] = 2*dot - sq[n] - sq[m]
__global__ __launch_bounds__(256) void dist_kernel(const float* __restrict__ y,
                                                   float* __restrict__ ws, int b) {
  __shared__ float As[32][65], Bs[32][65];
  const float* yb = y + (size_t)b * D3 * N_;      // [192][N]: row d = c*3+v
  const float* sq = ws + OFF_SQ + (size_t)b * N_;
  float* dist = ws + OFF_DIST;
  int t = threadIdx.x;
  int m0 = blockIdx.x * 64, n0 = blockIdx.y * 64;
  int og = t & 15, ng = t >> 4;
  float acc[4][4] = {};
  for (int dt = 0; dt < 6; ++dt) {
    __syncthreads();
    #pragma unroll
    for (int i = 0; i < 8; ++i) {
      int idx = t + i*256;
      int dd = idx >> 6, nl = idx & 63;
      As[dd][nl] = yb[(size_t)(dt*32 + dd)*N_ + n0 + nl];
      Bs[dd][nl] = yb[(size_t)(dt*32 + dd)*N_ + m0 + nl];
    }
    __syncthreads();
    for (int dd = 0; dd < 32; ++dd) {
      float av[4], bv[4];
      #pragma unroll
      for (int j = 0; j < 4; ++j) av[j] = As[dd][ng*4 + j];
      #pragma unroll
      for (int i = 0; i < 4; ++i) bv[i] = Bs[dd][og*4 + i];
      #pragma unroll
      for (int j = 0; j < 4; ++j)
        #pragma unroll
        for (int i = 0; i < 4; ++i) acc[j][i] = fmaf(av[j], bv[i], acc[j][i]);
    }
  }
  float sn[4], sm[4];
  #pragma unroll
  for (int j = 0; j < 4; ++j) sn[j] = sq[n0 + ng*4 + j];
  #pragma unroll
  for (int i = 0; i < 4; ++i) sm[i] = sq[m0 + og*4 + i];
  #pragma unroll
  for (int j = 0; j < 4; ++j) {
    float4 r;
    r.x = 2.f*acc[j][0] - sn[j] - sm[0];
    r.y = 2.f*acc[j][1] - sn[j] - sm[1];
    r.z = 2.f*acc[j][2] - sn[j] - sm[2];
    r.w = 2.f*acc[j][3] - sn[j] - sm[3];
    *(float4*)&dist[(size_t)(n0 + ng*4 + j)*N_ + m0 + og*4] = r;
  }
}

// grid (N), block 256: iterative argmax top-16 per row (ties -> lower index).
__global__ __launch_bounds__(256) void topk_kernel(const float* __restrict__ ws_c,
                                                   int* __restrict__ idxo, int b) {
  __shared__ float row[N_];
  __shared__ float wv_[4];
  __shared__ int   wi_[4];
  __shared__ int   bi_s;
  int n = blockIdx.x, t = threadIdx.x;
  const float* dr = ws_c + OFF_DIST + (size_t)n * N_;
  #pragma unroll
  for (int i = 0; i < 8; ++i) row[t + i*256] = dr[t + i*256];
  __syncthreads();
  for (int it = 0; it < K_; ++it) {
    float bv = -3.4e38f; int bi = 1 << 30;
    #pragma unroll
    for (int i = 0; i < 8; ++i) {
      int j = t + i*256;
      float v = row[j];
      if (v > bv || (v == bv && j < bi)) { bv = v; bi = j; }
    }
    #pragma unroll
    for (int off = 32; off > 0; off >>= 1) {
      float ov = __shfl_xor(bv, off, 64);
      int   oi = __shfl_xor(bi, off, 64);
      amax2(bv, bi, ov, oi);
    }
    if ((t & 63) == 0) { wv_[t >> 6] = bv; wi_[t >> 6] = bi; }
    __syncthreads();
    if (t == 0) {
      float fv = wv_[0]; int fi = wi_[0];
      for (int w = 1; w < 4; ++w) amax2(fv, fi, wv_[w], wi_[w]);
      bi_s = fi;
      idxo[((size_t)b*N_ + n)*K_ + it] = fi;
    }
    __syncthreads();
    int wi = bi_s;
    if (t == (wi & 255)) row[wi] = -3.4e38f;
    __syncthreads();
  }
}

// ---------------- BatchNorm statistics ----------------------------------------
// grid (N/128, B), block 256 (o = t&63, nl = t>>6): Q-branch norm stats.
__global__ __launch_bounds__(256) void qstats_kernel(float* __restrict__ ws) {
  int t = threadIdx.x, o = t & 63, nl = t >> 6;
  int n0 = blockIdx.x * 128, b = blockIdx.y;
  const float* pq = ws + OFF_PQ;
  float s1 = 0.f, s2 = 0.f;
  for (int j = 0; j < 32; ++j) {
    int n = n0 + nl + j*4;
    const float* r = pq + ((size_t)b*N_ + n)*D3 + o*3;
    float a = r[0], bb = r[1], cc = r[2];
    float norm = sqrtf(a*a + bb*bb + cc*cc) + EPS_;
    s1 += norm; s2 += norm*norm;
  }
  __shared__ float red[2][256];
  red[0][t] = s1; red[1][t] = s2;
  __syncthreads();
  if (t < 64) {
    float* st = ws + OFF_ST;
    float a1 = red[0][t] + red[0][t+64] + red[0][t+128] + red[0][t+192];
    float a2 = red[1][t] + red[1][t+64] + red[1][t+128] + red[1][t+192];
    atomicAdd(&st[t], a1);
    atomicAdd(&st[64 + t], a2);
  }
}

// grid (N*K/128, B), block 256: K- and V-branch norm stats (gathered).
__global__ __launch_bounds__(256) void kvstats_kernel(float* __restrict__ ws,
                                                      const int* __restrict__ idxp) {
  int t = threadIdx.x, o = t & 63, eg = t >> 6;
  int e0 = blockIdx.x * 128, b = blockIdx.y;
  const float* uK = ws + OFF_UK; const float* wK = ws + OFF_WK;
  const float* uV = ws + OFF_UV; const float* wV = ws + OFF_WV;
  float k1 = 0.f, k2 = 0.f, v1 = 0.f, v2 = 0.f;
  for (int j = 0; j < 32; ++j) {
    int e = e0 + eg + j*4;
    int n = e >> 4, kk = e & 15;
    int m = idxp[((size_t)b*N_ + n)*K_ + kk];
    size_t rb = ((size_t)b*N_ + n)*D3 + o*3;
    size_t gb = ((size_t)b*N_ + m)*D3 + o*3;
    float p0 = uK[gb] + wK[rb], p1 = uK[gb+1] + wK[rb+1], p2 = uK[gb+2] + wK[rb+2];
    float nk = sqrtf(p0*p0 + p1*p1 + p2*p2) + EPS_;
    k1 += nk; k2 += nk*nk;
    float q0 = uV[gb] + wV[rb], q1 = uV[gb+1] + wV[rb+1], q2 = uV[gb+2] + wV[rb+2];
    float nv = sqrtf(q0*q0 + q1*q1 + q2*q2) + EPS_;
    v1 += nv; v2 += nv*nv;
  }
  __shared__ float red[4][256];
  red[0][t] = k1; red[1][t] = k2; red[2][t] = v1; red[3][t] = v2;
  __syncthreads();
  if (t < 64) {
    float* st = ws + OFF_ST;
    float a = red[0][t] + red[0][t+64] + red[0][t+128] + red[0][t+192];
    atomicAdd(&st[128 + t], a);
    a = red[1][t] + red[1][t+64] + red[1][t+128] + red[1][t+192];
    atomicAdd(&st[192 + t], a);
    a = red[2][t] + red[2][t+64] + red[2][t+128] + red[2][t+192];
    atomicAdd(&st[256 + t], a);
    a = red[3][t] + red[3][t+64] + red[3][t+128] + red[3][t+192];
    atomicAdd(&st[320 + t], a);
  }
}

// 1 block, 64 threads: fold BN into scale/shift: norm_bn = norm*s + sh
__global__ void bn_finalize(const float* __restrict__ gq, const float* __restrict__ bq,
                            const float* __restrict__ gk, const float* __restrict__ bk,
                            const float* __restrict__ gv, const float* __restrict__ bv,
                            float* __restrict__ ws) {
  int o = threadIdx.x;
  if (o >= 64) return;
  float* st = ws + OFF_ST;
  float cq = (float)(B_ * N_);
  float mu = st[o] / cq;
  float var = fmaxf(st[64+o]/cq - mu*mu, 0.f);
  float s = gq[o] * rsqrtf(var + BNE_);
  st[384+o] = s; st[448+o] = bq[o] - mu*s;
  float ck = (float)(B_ * N_ * K_);
  mu = st[128+o] / ck;
  var = fmaxf(st[192+o]/ck - mu*mu, 0.f);
  s = gk[o] * rsqrtf(var + BNE_);
  st[512+o] = s; st[576+o] = bk[o] - mu*s;
  mu = st[256+o] / ck;
  var = fmaxf(st[320+o]/ck - mu*mu, 0.f);
  s = gv[o] * rsqrtf(var + BNE_);
  st[640+o] = s; st[704+o] = bv[o] - mu*s;
}

// grid (N/4, B), block 256 (o = t&63, wave = one n): finish Q branch + chnorm.
__global__ __launch_bounds__(256) void qx_final(float* __restrict__ ws) {
  int t = threadIdx.x, o = t & 63, nl = t >> 6;
  int n = blockIdx.x * 4 + nl, b = blockIdx.y;
  const float* pq = ws + OFF_PQ; const float* dq = ws + OFF_DQ;
  const float* st = ws + OFF_ST;
  float* Qx = ws + OFF_QX;
  size_t rb = ((size_t)b*N_ + n)*D3 + o*3;
  float p0 = pq[rb], p1 = pq[rb+1], p2 = pq[rb+2];
  float d0 = dq[rb], d1 = dq[rb+1], d2 = dq[rb+2];
  vnlk(p0, p1, p2, d0, d1, d2, st[384+o], st[448+o]);
  float nc2 = p0*p0 + p1*p1 + p2*p2;
  float tot = wred_sum(nc2);
  float nc = sqrtf(nc2), nch = sqrtf(tot);
  float sc = nc / (fmaxf(nc, 1e-12f) * fmaxf(nch, 1e-12f));
  Qx[rb] = p0*sc; Qx[rb+1] = p1*sc; Qx[rb+2] = p2*sc;
}

// grid (N, B), block 256 (o = t&63, kg = t>>6): gather K/V, BN+leaky, chnorm(K),
// qk, softmax over 16, weighted V sum, add x, write out.
__global__ __launch_bounds__(256) void final_kernel(const float* __restrict__ x,
                                                    const float* __restrict__ ws_c,
                                                    const int* __restrict__ idxp,
                                                    float* __restrict__ out) {
  const float* uK  = ws_c + OFF_UK;  const float* wK  = ws_c + OFF_WK;
  const float* uDk = ws_c + OFF_UDK; const float* wDk = ws_c + OFF_WDK;
  const float* uV  = ws_c + OFF_UV;  const float* wV  = ws_c + OFF_WV;
  const float* uDv = ws_c + OFF_UDV; const float* wDv = ws_c + OFF_WDV;
  const float* Qx  = ws_c + OFF_QX;  const float* st  = ws_c + OFF_ST;
  int t = threadIdx.x, o = t & 63, kg = t >> 6;
  int n = blockIdx.x, b = blockIdx.y;
  __shared__ int   mi[16];
  __shared__ float qkb[64][17];
  __shared__ float ob[64][12];
  if (t < 16) mi[t] = idxp[((size_t)b*N_ + n)*K_ + t];
  __syncthreads();
  size_t rb = ((size_t)b*N_ + n)*D3 + o*3;
  float wk0 = wK[rb],  wk1 = wK[rb+1],  wk2 = wK[rb+2];
  float wdk0= wDk[rb], wdk1= wDk[rb+1], wdk2= wDk[rb+2];
  float wv0 = wV[rb],  wv1 = wV[rb+1],  wv2 = wV[rb+2];
  float wdv0= wDv[rb], wdv1= wDv[rb+1], wdv2= wDv[rb+2];
  float qx0 = Qx[rb],  qx1 = Qx[rb+1],  qx2 = Qx[rb+2];
  float sK = st[512+o], shK = st[576+o], sV = st[640+o], shV = st[704+o];
  const float isq = 0.07216878364870323f;   // 1/sqrt(3*C) = 1/sqrt(192)
  float qkr[4], vy[4][3];
  #pragma unroll
  for (int j = 0; j < 4; ++j) {
    int kk = kg*4 + j;
    int m = mi[kk];
    size_t gb = ((size_t)b*N_ + m)*D3 + o*3;
    // K branch
    float p0 = uK[gb] + wk0, p1 = uK[gb+1] + wk1, p2 = uK[gb+2] + wk2;
    float e0 = uDk[gb] + wdk0, e1 = uDk[gb+1] + wdk1, e2 = uDk[gb+2] + wdk2;
    vnlk(p0, p1, p2, e0, e1, e2, sK, shK);
    float nc2 = p0*p0 + p1*p1 + p2*p2;
    float tot = wred_sum(nc2);                       // over 64 channels (one wave)
    float nc = sqrtf(nc2), nch = sqrtf(tot);
    float sc = nc / (fmaxf(nc, 1e-12f) * fmaxf(nch, 1e-12f));
    float q = (p0*qx0 + p1*qx1 + p2*qx2) * sc * isq;
    qkr[j] = q;
    qkb[o][kk] = q;
    // V branch
    float v0 = uV[gb] + wv0, v1 = uV[gb+1] + wv1, v2 = uV[gb+2] + wv2;
    float f0 = uDv[gb] + wdv0, f1 = uDv[gb+1] + wdv1, f2 = uDv[gb+2] + wdv2;
    vnlk(v0, v1, v2, f0, f1, f2, sV, shV);
    vy[j][0] = v0; vy[j][1] = v1; vy[j][2] = v2;
  }
  __syncthreads();
  float mx = -3.4e38f;
  #pragma unroll
  for (int kk = 0; kk < 16; ++kk) mx = fmaxf(mx, qkb[o][kk]);
  float se = 0.f;
  #pragma unroll
  for (int kk = 0; kk < 16; ++kk) se += expf(qkb[o][kk] - mx);
  float inv = 1.f / se;
  float a0 = 0.f, a1 = 0.f, a2 = 0.f;
  #pragma unroll
  for (int j = 0; j < 4; ++j) {
    float at = expf(qkr[j] - mx) * inv;
    a0 = fmaf(at, vy[j][0], a0);
    a1 = fmaf(at, vy[j][1], a1);
    a2 = fmaf(at, vy[j][2], a2);
  }
  ob[o][0 + kg] = a0; ob[o][4 + kg] = a1; ob[o][8 + kg] = a2;
  __syncthreads();
  if (t < 192) {
    int o2 = t / 3, v2 = t - o2*3;
    const float* r = &ob[o2][v2*4];
    float sm = r[0] + r[1] + r[2] + r[3];
    size_t xo = (((size_t)b*C_ + o2)*3 + v2)*N_ + n;
    out[xo] = x[xo] + sm;
  }
}

extern "C" void kernel_launch(void* const* d_in, const int* in_sizes, int n_in,
                              void* d_out, int out_size, void* d_ws, size_t ws_size,
                              hipStream_t stream) {
  const float* x  = (const float*)d_in[0];
  const float* y  = (const float*)d_in[1];
  const float* Wq = (const float*)d_in[2];
  const float* Dq = (const float*)d_in[3];
  const float* gq = (const float*)d_in[4];
  const float* bq = (const float*)d_in[5];
  const float* Wk = (const float*)d_in[6];
  const float* Dk = (const float*)d_in[7];
  const float* gk = (const float*)d_in[8];
  const float* bk = (const float*)d_in[9];
  const float* Wv = (const float*)d_in[10];
  const float* Dv = (const float*)d_in[11];
  const float* gv = (const float*)d_in[12];
  const float* bv = (const float*)d_in[13];
  float* ws = (float*)d_ws;
  float* out = (float*)d_out;
  int* idxp = (int*)(ws + OFF_IDX);

  hipMemsetAsync((void*)(ws + OFF_ST), 0, 1024 * sizeof(float), stream);
  transform_kernel<<<dim3(N_/64, B_, 2), 256, 0, stream>>>(x, y, Wq, Dq, Wk, Dk, Wv, Dv, ws);
  for (int b = 0; b < B_; ++b) {
    dist_kernel<<<dim3(N_/64, N_/64), 256, 0, stream>>>(y, ws, b);
    topk_kernel<<<dim3(N_), 256, 0, stream>>>(ws, idxp, b);
  }
  qstats_kernel<<<dim3(N_/128, B_), 256, 0, stream>>>(ws);
  kvstats_kernel<<<dim3(N_*K_/128, B_), 256, 0, stream>>>(ws, idxp);
  bn_finalize<<<1, 64, 0, stream>>>(gq, bq, gk, bk, gv, bv, ws);
  qx_final<<<dim3(N_/4, B_), 256, 0, stream>>>(ws);
  final_kernel<<<dim3(N_, B_), 256, 0, stream>>>(x, ws, idxp, out);
}